// Round 12
// baseline (21.410 us; speedup 1.0000x reference)
//
#include <hip/hip_runtime.h>
#include <math.h>

#define HWp 65536   // 256*256

typedef float v2f __attribute__((ext_vector_type(2)));
typedef float v4f __attribute__((ext_vector_type(4)));

__device__ __forceinline__ v2f fma2(v2f a, v2f b, v2f c) {
    return __builtin_elementwise_fma(a, b, c);   // v_pk_fma_f32
}
__device__ __forceinline__ void stream_st4(float* p, v4f v) {
    __builtin_nontemporal_store(v, (v4f*)p);     // 16B nt store
}
__device__ __forceinline__ float vget(v2f v, int px) { return px ? v.y : v.x; }

// tile row for S plane (i,j): unique entries enumerated col n=min, row r=max
__host__ __device__ constexpr int TRW(int p) {
    const int i = p / 6, j = p % 6;
    const int n = (i < j) ? i : j;
    const int r = (i < j) ? j : i;
    return 6*n - (n*(n-1))/2 + (r - n);
}

__global__ __launch_bounds__(256)
void gp_encoder_kernel(const float* __restrict__ x,
                       const float* __restrict__ Wt,
                       const float* __restrict__ be,
                       float* __restrict__ out)
{
    // unified store-transpose tile, one full image row (256 px) per block.
    // rows: 0..20 = S unique entries (TRW), 21..26 = m, 27..29 = xf,
    //       30..35 = d (transient; consumed before y), 33..35 = y (after d dead)
    __shared__ float T[36][260];   // 37,440 B -> 4 blocks/CU

    const int tid  = threadIdx.x;
    const int lane = tid & 63;
    const int wid  = tid >> 6;        // 0,1 = A halves (R/S/tail); 2,3 = B halves (conv m/s/xf)
    const bool isA = wid < 2;
    const int  half = wid & 1;        // which 128-px half of the row

    // one block = one image row
    const int blk  = blockIdx.x;      // 1024 blocks
    const int b    = blk >> 8;        // image
    const int h    = blk & 255;       // row
    const int pixb = h << 8;

    const int  ph = half << 7;        // 0 or 128
    const int  c0 = ph + 2 * lane;    // row-local column of pixel0
    const bool wlo_ok = (c0 != 0);
    const bool whi_ok = (c0 != 254);
    const int  idx_l  = wlo_ok ? c0 - 1 : c0;
    const int  idx_r  = whi_ok ? c0 + 2 : c0;

    // ---------------- taps for BOTH pixels: 27 v2f ----------------
    v2f tp[27];
    #pragma unroll
    for (int ci = 0; ci < 3; ++ci) {
        #pragma unroll
        for (int kh = 0; kh < 3; ++kh) {
            const int hh = h + kh - 1;     // scalar
            float lv = 0.f, rv = 0.f;
            v2f   mv = (v2f){0.f, 0.f};
            if ((unsigned)hh < 256u) {     // uniform branch
                const float* rp = x + (b*3 + ci) * HWp + hh * 256;
                mv = *reinterpret_cast<const v2f*>(rp + c0);
                lv = rp[idx_l];
                rv = rp[idx_r];
                lv = wlo_ok ? lv : 0.f;
                rv = whi_ok ? rv : 0.f;
            }
            tp[ci*9 + kh*3 + 0] = (v2f){lv, mv.x};
            tp[ci*9 + kh*3 + 1] = mv;
            tp[ci*9 + kh*3 + 2] = (v2f){mv.y, rv};
        }
    }

    auto conv_ch = [&](int ch) -> v2f {
        const float bb = be[ch];
        v2f acc = (v2f){bb, bb};
        const float* wp = Wt + ch * 27;
        #pragma unroll
        for (int t = 0; t < 27; ++t) {
            const float wt = wp[t];
            acc = fma2(tp[t], (v2f){wt, wt}, acc);
        }
        return acc;
    };

    // scalar output-section bases (row origin)
    float* out_xf = out                      + b*3*HWp  + pixb;
    float* out_m  = out + 4*3*HWp            + b*6*HWp  + pixb;
    float* out_S  = out + (4*3+4*6)*HWp      + b*36*HWp + pixb;
    float* out_y  = out + (4*3+4*6+4*36)*HWp + b*3*HWp  + pixb;

    if (!isA) {
        // ======== wave B: conv(m/s/xf) -> publish m, xf, d into tile ========
        #pragma unroll
        for (int o = 0; o < 6; ++o)
            *reinterpret_cast<v2f*>(&T[21 + o][c0]) = conv_ch(o);       // m
        #pragma unroll
        for (int o = 0; o < 3; ++o)
            *reinterpret_cast<v2f*>(&T[27 + o][c0]) = conv_ch(27 + o);  // xf
        #pragma unroll
        for (int o = 0; o < 6; ++o) {
            const v2f s = conv_ch(6 + o);                                // d
            *reinterpret_cast<v2f*>(&T[30 + o][c0]) =
                __builtin_elementwise_max(s * s, (v2f){1e-6f, 1e-6f});
        }

        __syncthreads();   // bar1: release A
        __syncthreads();   // bar2: wait for A's S + y tile writes
    } else {
        // ======== wave A: conv(angle) -> trig -> Givens -> S -> tail ========
        v2f pa[15];
        #pragma unroll
        for (int o = 0; o < 15; ++o)
            pa[o] = conv_ch(12 + o);

        // sigmoid + sin/cos of 2*pi*sg (HW trig takes revolutions)
        v2f cs[15], ss[15];
        #pragma unroll
        for (int k = 0; k < 15; ++k) {
            const float e0 = __expf(-pa[k].x);
            const float e1 = __expf(-pa[k].y);
            const float g0 = __builtin_amdgcn_rcpf(1.f + e0);
            const float g1 = __builtin_amdgcn_rcpf(1.f + e1);
            cs[k] = (v2f){__builtin_amdgcn_cosf(g0), __builtin_amdgcn_cosf(g1)};
            ss[k] = (v2f){__builtin_amdgcn_sinf(g0), __builtin_amdgcn_sinf(g1)};
        }

        v2f R[6][6];
        #pragma unroll
        for (int r = 0; r < 6; ++r)
            #pragma unroll
            for (int c = 0; c < 6; ++c)
                R[r][c] = (r == c) ? (v2f){1.f, 1.f} : (v2f){0.f, 0.f};

        const int PI_[15] = {0,0,0,0,0,1,1,1,1,2,2,2,3,3,4};
        const int PJ_[15] = {1,2,3,4,5,2,3,4,5,3,4,5,4,5,5};
        #pragma unroll
        for (int k = 0; k < 15; ++k) {
            const int i = PI_[k], j = PJ_[k];
            const v2f c2 = cs[k], s2 = ss[k];
            #pragma unroll
            for (int r = 0; r < 6; ++r) {
                const v2f ri = R[r][i], rj = R[r][j];
                R[r][i] = fma2(c2, ri, s2 * rj);
                R[r][j] = fma2(c2, rj, -(s2 * ri));
            }
        }

        __syncthreads();   // bar1: m, xf, d ready in tile

        v2f dk[6], mm[6], xx[3];
        #pragma unroll
        for (int k = 0; k < 6; ++k) dk[k] = *reinterpret_cast<const v2f*>(&T[30 + k][c0]);
        #pragma unroll
        for (int k = 0; k < 6; ++k) mm[k] = *reinterpret_cast<const v2f*>(&T[21 + k][c0]);
        #pragma unroll
        for (int k = 0; k < 3; ++k) xx[k] = *reinterpret_cast<const v2f*>(&T[27 + k][c0]);

        // S = R diag(d) R^T: 21 unique entries -> tile; keep syx/syy for tail
        v2f syx2[3][3], syy2[3][3];
        #pragma unroll
        for (int n = 0; n < 6; ++n) {
            v2f t[6];
            #pragma unroll
            for (int k = 0; k < 6; ++k)
                t[k] = dk[k] * R[n][k];
            #pragma unroll
            for (int r = n; r < 6; ++r) {
                v2f acc = t[0] * R[r][0];
                #pragma unroll
                for (int k = 1; k < 6; ++k)
                    acc = fma2(t[k], R[r][k], acc);
                *reinterpret_cast<v2f*>(&T[TRW(r*6 + n)][c0]) = acc;
                if (r >= 3 && n < 3)  syx2[r-3][n] = acc;
                if (r >= 3 && n >= 3) { syy2[r-3][n-3] = acc;
                                        if (r != n) syy2[n-3][r-3] = acc; }
            }
        }

        // f64 tail: Q = -S_yy^{-1} S_yx (exact identity), y = my - Qp(xf - mx)
        float yv[2][3];
        #pragma unroll
        for (int px = 0; px < 2; ++px) {
            const double a00 = (double)vget(syy2[0][0], px), a01 = (double)vget(syy2[0][1], px), a02 = (double)vget(syy2[0][2], px);
            const double a10 = (double)vget(syy2[1][0], px), a11 = (double)vget(syy2[1][1], px), a12 = (double)vget(syy2[1][2], px);
            const double a20 = (double)vget(syy2[2][0], px), a21 = (double)vget(syy2[2][1], px), a22 = (double)vget(syy2[2][2], px);

            const double det = a00*(a11*a22 - a12*a21)
                             - a01*(a10*a22 - a12*a20)
                             + a02*(a10*a21 - a11*a20);
            const double idet = 1.0 / det;

            double inv[3][3];
            inv[0][0] =  (a11*a22 - a12*a21) * idet;
            inv[0][1] = -(a01*a22 - a02*a21) * idet;
            inv[0][2] =  (a01*a12 - a02*a11) * idet;
            inv[1][0] = -(a10*a22 - a12*a20) * idet;
            inv[1][1] =  (a00*a22 - a02*a20) * idet;
            inv[1][2] = -(a00*a12 - a02*a10) * idet;
            inv[2][0] =  (a10*a21 - a11*a20) * idet;
            inv[2][1] = -(a00*a21 - a01*a20) * idet;
            inv[2][2] =  (a00*a11 - a01*a10) * idet;

            double Qp[3][3];
            #pragma unroll
            for (int r = 0; r < 3; ++r)
                #pragma unroll
                for (int c = 0; c < 3; ++c) {
                    double acc = 0.0;
                    #pragma unroll
                    for (int k = 0; k < 3; ++k)
                        acc = fma(inv[r][k], (double)vget(syx2[k][c], px), acc);
                    Qp[r][c] = acc;
                }

            #pragma unroll
            for (int i = 0; i < 3; ++i) {
                double acc = (double)vget(mm[3 + i], px);
                #pragma unroll
                for (int n = 0; n < 3; ++n)
                    acc = fma(-Qp[i][n], (double)vget(xx[n], px) - (double)vget(mm[n], px), acc);
                yv[px][i] = (float)acc;
            }
        }

        // y into tile rows 33..35 (d rows; d fully consumed above)
        #pragma unroll
        for (int i = 0; i < 3; ++i)
            *reinterpret_cast<v2f*>(&T[33 + i][c0]) = (v2f){yv[0][i], yv[1][i]};

        __syncthreads();   // bar2: tile complete
    }

    // ======== cooperative store phase: 48 planes x 1KB nt dwordx4, 12/wave ========
    #define STP(base, pl, row) { \
        v4f v = *reinterpret_cast<const v4f*>(&T[(row)][4*lane]); \
        stream_st4(&(base)[(pl)*HWp + 4*lane], v); }

    switch (wid) {
      case 0:
        STP(out_S, 0, TRW(0))  STP(out_S, 1, TRW(1))  STP(out_S, 2, TRW(2))
        STP(out_S, 3, TRW(3))  STP(out_S, 4, TRW(4))  STP(out_S, 5, TRW(5))
        STP(out_S, 6, TRW(6))  STP(out_S, 7, TRW(7))  STP(out_S, 8, TRW(8))
        STP(out_S, 9, TRW(9))  STP(out_S,10, TRW(10)) STP(out_S,11, TRW(11))
        break;
      case 1:
        STP(out_S,12, TRW(12)) STP(out_S,13, TRW(13)) STP(out_S,14, TRW(14))
        STP(out_S,15, TRW(15)) STP(out_S,16, TRW(16)) STP(out_S,17, TRW(17))
        STP(out_S,18, TRW(18)) STP(out_S,19, TRW(19)) STP(out_S,20, TRW(20))
        STP(out_S,21, TRW(21)) STP(out_S,22, TRW(22)) STP(out_S,23, TRW(23))
        break;
      case 2:
        STP(out_S,24, TRW(24)) STP(out_S,25, TRW(25)) STP(out_S,26, TRW(26))
        STP(out_S,27, TRW(27)) STP(out_S,28, TRW(28)) STP(out_S,29, TRW(29))
        STP(out_S,30, TRW(30)) STP(out_S,31, TRW(31)) STP(out_S,32, TRW(32))
        STP(out_S,33, TRW(33)) STP(out_S,34, TRW(34)) STP(out_S,35, TRW(35))
        break;
      default:
        STP(out_m, 0, 21) STP(out_m, 1, 22) STP(out_m, 2, 23)
        STP(out_m, 3, 24) STP(out_m, 4, 25) STP(out_m, 5, 26)
        STP(out_xf,0, 27) STP(out_xf,1, 28) STP(out_xf,2, 29)
        STP(out_y, 0, 33) STP(out_y, 1, 34) STP(out_y, 2, 35)
        break;
    }
    #undef STP
}

extern "C" void kernel_launch(void* const* d_in, const int* in_sizes, int n_in,
                              void* d_out, int out_size, void* d_ws, size_t ws_size,
                              hipStream_t stream) {
    const float* x  = (const float*)d_in[0];
    const float* Wt = (const float*)d_in[1];
    const float* be = (const float*)d_in[2];
    float* out = (float*)d_out;

    dim3 grid(1024);   // 4 images x 256 rows; one row per block
    dim3 block(256);   // A0,A1 (R/S/tail) + B0,B1 (conv m/s/xf); all 4 store
    hipLaunchKernelGGL(gp_encoder_kernel, grid, block, 0, stream, x, Wt, be, out);
}